// Round 17
// baseline (1159.203 us; speedup 1.0000x reference)
//
#include <hip/hip_runtime.h>
#include <cstdint>
#include <cstring>
#include <cmath>

#define NEDGE 65536
#define NNODE 4096
#define FDIM  64
#define LMDIM 16
#define NPATHS 23
#define HDIM  64
#define NSPEC 10
#define RWN   (NPATHS*FDIM)                    // 1472
#define NF16  ((size_t)NNODE * FDIM * LMDIM)   // 4,194,304 floats
#define STGCAP 17088                           // staged edges per chunk
#define CHUNKN 1024                            // nodes per chunk
#define NCHUNK (NNODE/CHUNKN)                  // 4
#define NWAVE 4                                // waves per gather block
#define LINB  8                                // nodes per lin block

typedef __attribute__((ext_vector_type(8))) short bf16x8;
typedef __attribute__((ext_vector_type(4))) float f32x4;

__device__ __forceinline__ unsigned short f32_to_bf16_rne(float v)
{
    uint32_t bits;
    __builtin_memcpy(&bits, &v, 4);
    bits += 0x7fffu + ((bits >> 16) & 1u);
    return (unsigned short)(bits >> 16);
}

// ===========================================================================
// Compile-time Clebsch-Gordan coefficients (constexpr; no device tables)
// ===========================================================================

struct cxd { double re, im; };
constexpr cxd cmul_(cxd a, cxd b){ return {a.re*b.re - a.im*b.im, a.re*b.im + a.im*b.re}; }
constexpr cxd cadd_(cxd a, cxd b){ return {a.re + b.re, a.im + b.im}; }

constexpr double csqrt_(double x)
{
    if (x <= 0.0) return 0.0;
    double g = (x < 1.0) ? 1.0 : x;
    for (int i = 0; i < 30; i++) g = 0.5*(g + x/g);
    return g;
}

constexpr double su2_c_(int j1, int j2, int j3, int m1, int m2, int m3,
                        const double* F)
{
    if (m1 + m2 != m3) return 0.0;
    int vmin = -j1 + j2 + m3; if (-j1 + m1 > vmin) vmin = -j1 + m1; if (vmin < 0) vmin = 0;
    int vmax = j2 + j3 + m1; if (j3 - j1 + j2 < vmax) vmax = j3 - j1 + j2; if (j3 + m3 < vmax) vmax = j3 + m3;
    double C = csqrt_((2.0*j3 + 1.0) * F[j3+j1-j2] * F[j3-j1+j2] * F[j1+j2-j3] / F[j1+j2+j3+1])
             * csqrt_(F[j3+m3] * F[j3-m3] / (F[j1-m1] * F[j1+m1] * F[j2-m2] * F[j2+m2]));
    double S = 0.0;
    for (int v = vmin; v <= vmax; v++) {
        double t = F[j2+j3+m1-v] * F[j1-m1+v]
                 / (F[v] * F[j3-j1+j2-v] * F[j3+m3-v] * F[v+j1-j2-m3]);
        S += (((v + j2 + m2) & 1) ? -1.0 : 1.0) * t;
    }
    return C * S;
}

struct QM { cxd q[7][7]; };

constexpr QM qmat_c_(int l)
{
    QM Q{};
    double is2 = 1.0 / csqrt_(2.0);
    for (int m = -l; m < 0; m++) {
        Q.q[l+m][l-m] = cxd{is2, 0.0};
        Q.q[l+m][l+m] = cxd{0.0, -is2};
    }
    Q.q[l][l] = cxd{1.0, 0.0};
    for (int m = 1; m <= l; m++) {
        double s = (m & 1) ? -1.0 : 1.0;
        Q.q[l+m][l+m] = cxd{s*is2, 0.0};
        Q.q[l+m][l-m] = cxd{0.0, s*is2};
    }
    cxd ph = (l==0) ? cxd{1,0} : (l==1) ? cxd{0,-1} : (l==2) ? cxd{-1,0} : cxd{0,1};
    for (int a = 0; a < 7; a++)
        for (int b = 0; b < 7; b++)
            Q.q[a][b] = cmul_(Q.q[a][b], ph);
    return Q;
}

template<int L1, int L2, int L3>
struct CGPath { float v[(2*L1+1)*(2*L2+1)*(2*L3+1)]; };

template<int L1, int L2, int L3>
constexpr CGPath<L1,L2,L3> make_path_()
{
    constexpr int d1 = 2*L1+1, d2 = 2*L2+1, d3 = 2*L3+1;
    CGPath<L1,L2,L3> R{};
    double F[16] = {};
    F[0] = 1.0;
    for (int i = 1; i < 16; i++) F[i] = F[i-1] * i;
    QM q1 = qmat_c_(L1), q2 = qmat_c_(L2), q3 = qmat_c_(L3);
    double Cc[7][7][7] = {};
    for (int i = 0; i < d1; i++)
    for (int k = 0; k < d2; k++)
    for (int m = 0; m < d3; m++)
        Cc[i][k][m] = su2_c_(L1, L2, L3, i-L1, k-L2, m-L3, F);
    for (int jj = 0; jj < d1; jj++)
    for (int bb = 0; bb < d2; bb++)
    for (int cc = 0; cc < d3; cc++) {
        cxd s{0.0, 0.0};
        for (int i = 0; i < d1; i++) {
            cxd a = q1.q[i][jj];
            if (a.re == 0.0 && a.im == 0.0) continue;
            for (int k = 0; k < d2; k++) {
                cxd b = q2.q[k][bb];
                if (b.re == 0.0 && b.im == 0.0) continue;
                for (int m = 0; m < d3; m++) {
                    cxd g = q3.q[m][cc];
                    if (g.re == 0.0 && g.im == 0.0) continue;
                    double cg = Cc[i][k][m];
                    if (cg == 0.0) continue;
                    cxd gc = {g.re*cg, -g.im*cg};   // conj(q3)*cg
                    s = cadd_(s, cmul_(cmul_(a, b), gc));
                }
            }
        }
        R.v[(jj*d2 + bb)*d3 + cc] = (float)s.re;
    }
    return R;
}

// compile-time loop helper
template<int V> struct ic_ { static constexpr int value = V; };
template<int I, int N, typename F>
__device__ __forceinline__ void cfor_(F& f)
{
    if constexpr (I < N) { f(ic_<I>{}); cfor_<I+1, N>(f); }
}
template<int N, typename F>
__device__ __forceinline__ void cfor(F f) { cfor_<0, N>(f); }

// Sparse CG contraction with literal coefficients
template<int L1, int L2, int L3>
__device__ __forceinline__ void spath(const float* __restrict__ a1,
                                      const float* __restrict__ a2,
                                      float w, float* __restrict__ acc)
{
    constexpr CGPath<L1,L2,L3> P = make_path_<L1,L2,L3>();
    constexpr int d2 = 2*L2+1, d3 = 2*L3+1;
    float t[d3];
    #pragma unroll
    for (int k = 0; k < d3; k++) t[k] = 0.f;
    cfor<2*L1+1>([&](auto I) {
        cfor<d2>([&](auto J) {
            constexpr int i = decltype(I)::value;
            constexpr int j = decltype(J)::value;
            float pr = a1[i] * a2[j];
            (void)pr;
            cfor<d3>([&](auto K) {
                constexpr int k = decltype(K)::value;
                constexpr float c = P.v[(i*d2 + j)*d3 + k];
                if constexpr (c > 1e-10f || c < -1e-10f)
                    t[k] = fmaf(c, pr, t[k]);
            });
        });
    });
    #pragma unroll
    for (int k = 0; k < d3; k++) acc[k] = fmaf(w, t[k], acc[k]);
}

#define SALLP(A1, A2, W, ACC)                       \
    spath<0,0,0>(A1+0, A2+0, (W)[ 0], ACC+0);       \
    spath<0,1,1>(A1+0, A2+1, (W)[ 1], ACC+1);       \
    spath<0,2,2>(A1+0, A2+4, (W)[ 2], ACC+4);       \
    spath<0,3,3>(A1+0, A2+9, (W)[ 3], ACC+9);       \
    spath<1,0,1>(A1+1, A2+0, (W)[ 4], ACC+1);       \
    spath<1,1,0>(A1+1, A2+1, (W)[ 5], ACC+0);       \
    spath<1,1,2>(A1+1, A2+1, (W)[ 6], ACC+4);       \
    spath<1,2,1>(A1+1, A2+4, (W)[ 7], ACC+1);       \
    spath<1,2,3>(A1+1, A2+4, (W)[ 8], ACC+9);       \
    spath<1,3,2>(A1+1, A2+9, (W)[ 9], ACC+4);       \
    spath<2,0,2>(A1+4, A2+0, (W)[10], ACC+4);       \
    spath<2,1,1>(A1+4, A2+1, (W)[11], ACC+1);       \
    spath<2,1,3>(A1+4, A2+1, (W)[12], ACC+9);       \
    spath<2,2,0>(A1+4, A2+4, (W)[13], ACC+0);       \
    spath<2,2,2>(A1+4, A2+4, (W)[14], ACC+4);       \
    spath<2,3,1>(A1+4, A2+9, (W)[15], ACC+1);       \
    spath<2,3,3>(A1+4, A2+9, (W)[16], ACC+9);       \
    spath<3,0,3>(A1+9, A2+0, (W)[17], ACC+9);       \
    spath<3,1,2>(A1+9, A2+1, (W)[18], ACC+4);       \
    spath<3,2,1>(A1+9, A2+4, (W)[19], ACC+1);       \
    spath<3,2,3>(A1+9, A2+4, (W)[20], ACC+9);       \
    spath<3,3,0>(A1+9, A2+9, (W)[21], ACC+0);       \
    spath<3,3,2>(A1+9, A2+9, (W)[22], ACC+4);

// ---------------------------------------------------------------------------
// Geometry
// ---------------------------------------------------------------------------

__global__ void mace_geom_kernel(const float* __restrict__ vec,
                                 float* __restrict__ ysh, float* __restrict__ rbf)
{
    int e = blockIdx.x * blockDim.x + threadIdx.x;
    if (e >= NEDGE) return;
    float x = vec[3*e+0], y = vec[3*e+1], z = vec[3*e+2];
    float r = sqrtf(x*x + y*y + z*z);
    float inv = 1.0f / (r + 1e-9f);
    float ux = x*inv, uy = y*inv, uz = z*inv;

    const float s3    = 1.7320508075688772f;
    const float s5_2  = 1.1180339887498949f;
    const float s15   = 3.8729833462074170f;
    const float s15_2 = 1.9364916731037085f;
    const float s35_8 = 2.0916500663351889f;
    const float s105  = 10.246950765959598f;
    const float s21_8 = 1.6201851746019651f;
    const float s7_2  = 1.3228756555322954f;
    const float s105_2= 5.1234753829797990f;

    float* Y = ysh + (size_t)e * 16;
    Y[0]  = 1.0f;
    Y[1]  = s3 * uy;
    Y[2]  = s3 * uz;
    Y[3]  = s3 * ux;
    Y[4]  = s15 * ux * uy;
    Y[5]  = s15 * uy * uz;
    Y[6]  = s5_2 * (3.f*uz*uz - 1.f);
    Y[7]  = s15 * ux * uz;
    Y[8]  = s15_2 * (ux*ux - uy*uy);
    Y[9]  = s35_8 * uy * (3.f*ux*ux - uy*uy);
    Y[10] = s105 * ux * uy * uz;
    Y[11] = s21_8 * uy * (5.f*uz*uz - 1.f);
    Y[12] = s7_2 * uz * (5.f*uz*uz - 3.f);
    Y[13] = s21_8 * ux * (5.f*uz*uz - 1.f);
    Y[14] = s105_2 * uz * (ux*ux - uy*uy);
    Y[15] = s35_8 * ux * (ux*ux - 3.f*uy*uy);

    float env = 0.f;
    if (r < 1.f) {
        float r2 = r*r, r3 = r2*r, r6 = r3*r3, r7 = r6*r, r8 = r7*r;
        env = 1.f - 28.f*r6 + 48.f*r7 - 21.f*r8;
    }
    const float sq2 = 1.4142135623730951f;
    const float PI_ = 3.14159265358979323846f;
    float* R = rbf + (size_t)e * 8;
    #pragma unroll
    for (int n = 1; n <= 8; n++)
        R[n-1] = sq2 * sinf(PI_ * (float)n * r) * inv * env;
}

__global__ void mace_init_h_kernel(const int* __restrict__ spec,
                                   const float* __restrict__ embed,
                                   float* __restrict__ h)
{
    int idx = blockIdx.x * blockDim.x + threadIdx.x;
    int n = idx >> 10;
    int t = idx & 1023;
    int f = t >> 4, m = t & 15;
    h[idx] = (m == 0) ? embed[spec[n]*FDIM + f] : 0.f;
}

// radial: silu(rbf @ W1) -> bf16 directly (GEMM input)
__global__ void mace_radial_kernel(const float* __restrict__ rbf,
                                   const float* __restrict__ W1,
                                   unsigned short* __restrict__ hidb)
{
    int idx = blockIdx.x * blockDim.x + threadIdx.x;   // NEDGE*64
    int e = idx >> 6, j = idx & 63;
    float a = 0.f;
    #pragma unroll
    for (int n = 0; n < 8; n++)
        a = fmaf(rbf[(size_t)e*8 + n], W1[n*64 + j], a);
    hidb[idx] = f32_to_bf16_rne(a / (1.f + expf(-a)));
}

// W2t[n][h] bf16 = W2[h][n]
__global__ void w2t_kernel(const float* __restrict__ W2,
                           unsigned short* __restrict__ w2t)
{
    int idx = blockIdx.x * blockDim.x + threadIdx.x;   // RWN*64
    if (idx >= RWN*64) return;
    int h = idx & 63, n = idx >> 6;
    w2t[idx] = f32_to_bf16_rne(W2[(size_t)h*RWN + n]);
}

// ---------------------------------------------------------------------------
// CSR build (edges by receiver) + species sort (nodes by species)
// ---------------------------------------------------------------------------

__global__ void csr_hist_kernel(const int* __restrict__ recv, int* __restrict__ cnt)
{
    int e = blockIdx.x * blockDim.x + threadIdx.x;
    if (e < NEDGE) atomicAdd(&cnt[recv[e]], 1);
}

__global__ void csr_scan_kernel(const int* __restrict__ cnt,
                                int* __restrict__ off, int* __restrict__ cur)
{
    __shared__ int part[1024];
    int t = threadIdx.x;
    int v0 = cnt[t*4+0], v1 = cnt[t*4+1], v2 = cnt[t*4+2], v3 = cnt[t*4+3];
    int sum = v0 + v1 + v2 + v3;
    part[t] = sum;
    __syncthreads();
    for (int d = 1; d < 1024; d <<= 1) {
        int x = (t >= d) ? part[t-d] : 0;
        __syncthreads();
        part[t] += x;
        __syncthreads();
    }
    int run = part[t] - sum;
    off[t*4+0] = run; cur[t*4+0] = run; run += v0;
    off[t*4+1] = run; cur[t*4+1] = run; run += v1;
    off[t*4+2] = run; cur[t*4+2] = run; run += v2;
    off[t*4+3] = run; cur[t*4+3] = run; run += v3;
    if (t == 1023) off[4096] = run;
}

__global__ void csr_scatter_kernel(const int* __restrict__ recv,
                                   int* __restrict__ cur, int* __restrict__ eidx)
{
    int e = blockIdx.x * blockDim.x + threadIdx.x;
    if (e < NEDGE) {
        int pos = atomicAdd(&cur[recv[e]], 1);
        eidx[pos] = e;
    }
}

__global__ void sp_hist_kernel(const int* __restrict__ spec, int* __restrict__ scnt)
{
    int n = blockIdx.x * blockDim.x + threadIdx.x;
    if (n < NNODE) atomicAdd(&scnt[spec[n]], 1);
}

__global__ void sp_scan_kernel(const int* __restrict__ scnt, int* __restrict__ scur)
{
    if (threadIdx.x == 0) {
        int run = 0;
        for (int s = 0; s < NSPEC; s++) { scur[s] = run; run += scnt[s]; }
    }
}

__global__ void sp_scatter_kernel(const int* __restrict__ spec,
                                  int* __restrict__ scur, int* __restrict__ snode)
{
    int n = blockIdx.x * blockDim.x + threadIdx.x;
    if (n < NNODE) {
        int pos = atomicAdd(&scur[spec[n]], 1);
        snode[pos] = n;
    }
}

// ---------------------------------------------------------------------------
// Chunked Rw GEMM via MFMA (bf16 in, bf16 out). No LDS, no barriers.
// ---------------------------------------------------------------------------

__global__ __launch_bounds__(256) void rw_gemm_chunk(
    const unsigned short* __restrict__ hidb,  // E x 64 bf16
    const unsigned short* __restrict__ w2t,   // 1472 x 64 bf16
    const int* __restrict__ offs,
    const int* __restrict__ eidx,
    int cb,
    unsigned short* __restrict__ stg)         // STGCAP x 1472 bf16
{
    int coff0 = offs[cb];
    int count = offs[cb + CHUNKN] - coff0;
    if (count > STGCAP) count = STGCAP;
    int e0 = blockIdx.x * 64;                 // edge base (N)
    if (e0 >= count) return;
    int n0 = blockIdx.y * 64;                 // w2-col base (M)
    int wv = threadIdx.x >> 6;                // m-strip 0..3
    int l  = threadIdx.x & 63;
    int lm = l & 15, q = l >> 4;

    const unsigned short* arow = w2t + (size_t)(n0 + wv*16 + lm) * 64 + q*8;
    bf16x8 a0 = *reinterpret_cast<const bf16x8*>(arow);
    bf16x8 a1 = *reinterpret_cast<const bf16x8*>(arow + 32);

    f32x4 acc[4];
    bool val[4];
    int erow[4];
    #pragma unroll
    for (int t = 0; t < 4; t++) {
        int row = e0 + t*16 + lm;
        val[t] = (row < count);
        erow[t] = eidx[coff0 + (val[t] ? row : 0)];
        acc[t] = (f32x4){0.f, 0.f, 0.f, 0.f};
    }
    #pragma unroll
    for (int t = 0; t < 4; t++) {
        const unsigned short* brow = hidb + (size_t)erow[t] * 64 + q*8;
        bf16x8 b0 = *reinterpret_cast<const bf16x8*>(brow);
        bf16x8 b1 = *reinterpret_cast<const bf16x8*>(brow + 32);
        acc[t] = __builtin_amdgcn_mfma_f32_16x16x32_bf16(a0, b0, acc[t], 0, 0, 0);
        acc[t] = __builtin_amdgcn_mfma_f32_16x16x32_bf16(a1, b1, acc[t], 0, 0, 0);
    }

    #pragma unroll
    for (int t = 0; t < 4; t++) {
        if (!val[t]) continue;
        int row = e0 + t*16 + lm;
        unsigned short u[4];
        u[0] = f32_to_bf16_rne(acc[t][0]);
        u[1] = f32_to_bf16_rne(acc[t][1]);
        u[2] = f32_to_bf16_rne(acc[t][2]);
        u[3] = f32_to_bf16_rne(acc[t][3]);
        uint2 pack;
        pack.x = (uint32_t)u[0] | ((uint32_t)u[1] << 16);
        pack.y = (uint32_t)u[2] | ((uint32_t)u[3] << 16);
        *reinterpret_cast<uint2*>(&stg[(size_t)row * RWN + n0 + wv*16 + q*4]) = pack;
    }
}

// ---------------------------------------------------------------------------
// Batched shared-weight lin: LINB nodes per block, weights register-resident.
// ---------------------------------------------------------------------------

__global__ __launch_bounds__(512, 2) void mace_lin_kernel(
    const float* __restrict__ in, const float* __restrict__ W,
    const float* __restrict__ add, float* __restrict__ out, float scale)
{
    __shared__ __align__(16) float st[LINB][16*68];
    int nb = blockIdx.x * LINB;
    int tid = threadIdx.x;

    #pragma unroll
    for (int j = 0; j < LINB; j++) {
        size_t base = (size_t)(nb + j) * 1024;
        float2 v = *reinterpret_cast<const float2*>(in + base + tid*2);
        int f = tid >> 3;
        int m = (tid & 7) * 2;
        st[j][m*68 + f]     = v.x;
        st[j][(m+1)*68 + f] = v.y;
    }
    __syncthreads();

    int fp = tid >> 4;          // 0..31
    int m  = tid & 15;
    int l  = (m == 0) ? 0 : (m < 4) ? 1 : (m < 9) ? 2 : 3;
    const float* Wl = W + l*4096;
    int f0 = fp * 2;

    float4 wa[16], wb[16];
    #pragma unroll
    for (int q = 0; q < 16; q++) {
        wa[q] = *reinterpret_cast<const float4*>(Wl + (size_t)f0*64 + q*4);
        wb[q] = *reinterpret_cast<const float4*>(Wl + (size_t)(f0+1)*64 + q*4);
    }

    #pragma unroll
    for (int j = 0; j < LINB; j++) {
        float ax = 0.f, ay = 0.f, az = 0.f, aw = 0.f;
        float bx = 0.f, by = 0.f, bz = 0.f, bw = 0.f;
        #pragma unroll
        for (int q = 0; q < 16; q++) {
            float4 sv = *reinterpret_cast<const float4*>(&st[j][m*68 + q*4]);
            ax = fmaf(wa[q].x, sv.x, ax); ay = fmaf(wa[q].y, sv.y, ay);
            az = fmaf(wa[q].z, sv.z, az); aw = fmaf(wa[q].w, sv.w, aw);
            bx = fmaf(wb[q].x, sv.x, bx); by = fmaf(wb[q].y, sv.y, by);
            bz = fmaf(wb[q].z, sv.z, bz); bw = fmaf(wb[q].w, sv.w, bw);
        }
        float a0 = ((ax + ay) + (az + aw)) * scale;
        float a1 = ((bx + by) + (bz + bw)) * scale;
        size_t o0 = (size_t)(nb + j) * 1024 + (size_t)f0*16 + m;
        if (add) { a0 += add[o0]; a1 += add[o0 + 16]; }
        out[o0] = a0;
        out[o0 + 16] = a1;
    }
}

// Species-sorted batched lin_sp
__global__ __launch_bounds__(512, 2) void mace_lin_sp_kernel(
    const float* __restrict__ in, const float* __restrict__ Wsp,
    const int* __restrict__ spec, const int* __restrict__ snode,
    const float* __restrict__ add, float* __restrict__ out)
{
    __shared__ __align__(16) float st[LINB][16*68];
    __shared__ int nodes[LINB];
    int nb = blockIdx.x * LINB;
    int tid = threadIdx.x;

    if (tid < LINB) nodes[tid] = snode[nb + tid];
    __syncthreads();

    #pragma unroll
    for (int j = 0; j < LINB; j++) {
        size_t base = (size_t)nodes[j] * 1024;
        float2 v = *reinterpret_cast<const float2*>(in + base + tid*2);
        int f = tid >> 3;
        int m = (tid & 7) * 2;
        st[j][m*68 + f]     = v.x;
        st[j][(m+1)*68 + f] = v.y;
    }
    __syncthreads();

    int fp = tid >> 4;
    int m  = tid & 15;
    int l  = (m == 0) ? 0 : (m < 4) ? 1 : (m < 9) ? 2 : 3;
    int f0 = fp * 2;

    int sp_cur = spec[nodes[0]];
    const float* Wl = Wsp + (size_t)sp_cur*4*4096 + l*4096;
    float4 wa[16], wb[16];
    #pragma unroll
    for (int q = 0; q < 16; q++) {
        wa[q] = *reinterpret_cast<const float4*>(Wl + (size_t)f0*64 + q*4);
        wb[q] = *reinterpret_cast<const float4*>(Wl + (size_t)(f0+1)*64 + q*4);
    }

    #pragma unroll
    for (int j = 0; j < LINB; j++) {
        int spj = spec[nodes[j]];
        if (spj != sp_cur) {
            sp_cur = spj;
            const float* Wl2 = Wsp + (size_t)sp_cur*4*4096 + l*4096;
            #pragma unroll
            for (int q = 0; q < 16; q++) {
                wa[q] = *reinterpret_cast<const float4*>(Wl2 + (size_t)f0*64 + q*4);
                wb[q] = *reinterpret_cast<const float4*>(Wl2 + (size_t)(f0+1)*64 + q*4);
            }
        }
        float ax = 0.f, ay = 0.f, az = 0.f, aw = 0.f;
        float bx = 0.f, by = 0.f, bz = 0.f, bw = 0.f;
        #pragma unroll
        for (int q = 0; q < 16; q++) {
            float4 sv = *reinterpret_cast<const float4*>(&st[j][m*68 + q*4]);
            ax = fmaf(wa[q].x, sv.x, ax); ay = fmaf(wa[q].y, sv.y, ay);
            az = fmaf(wa[q].z, sv.z, az); aw = fmaf(wa[q].w, sv.w, aw);
            bx = fmaf(wb[q].x, sv.x, bx); by = fmaf(wb[q].y, sv.y, by);
            bz = fmaf(wb[q].z, sv.z, bz); bw = fmaf(wb[q].w, sv.w, bw);
        }
        float a0 = (ax + ay) + (az + aw);
        float a1 = (bx + by) + (bz + bw);
        size_t o0 = (size_t)nodes[j] * 1024 + (size_t)f0*16 + m;
        if (add) { a0 += add[o0]; a1 += add[o0 + 16]; }
        out[o0] = a0;
        out[o0 + 16] = a1;
    }
}

// Compose Wc[sp][l][f][g] = eps * sum_k skipf[sp][l][f][k] * l2W[l][k][g]
__global__ __launch_bounds__(256) void compose_kernel(
    const float* __restrict__ skipf, const float* __restrict__ l2W,
    float* __restrict__ Wc, float eps)
{
    int idx = blockIdx.x * 256 + threadIdx.x;   // 10*4*64*64
    int g = idx & 63, f = (idx >> 6) & 63, l = (idx >> 12) & 3, sp = idx >> 14;
    const float* A = skipf + ((size_t)sp*4 + l)*4096 + f*64;
    const float* B = l2W + (size_t)l*4096 + g;
    float s0 = 0.f, s1 = 0.f;
    #pragma unroll 8
    for (int k = 0; k < 64; k += 2) {
        s0 = fmaf(A[k],   B[(size_t)k*64],        s0);
        s1 = fmaf(A[k+1], B[(size_t)(k+1)*64],    s1);
    }
    Wc[idx] = (s0 + s1) * eps;
}

// ---------------------------------------------------------------------------
// Message gather: 4 waves per node, software-pipelined (depth-1 data,
// depth-2 index prefetch) sparse literal-coefficient contraction.
// ---------------------------------------------------------------------------

__device__ __forceinline__ void gather_load(
    const float* __restrict__ h1, const float* __restrict__ ysh,
    const unsigned short* __restrict__ stg,
    int s, int e, int sidx, int f,
    float* hv, float* yv, float* rw)
{
    const float4* hp4 = reinterpret_cast<const float4*>(h1 + (size_t)s*1024 + f*16);
    float4 v0 = hp4[0], v1 = hp4[1], v2 = hp4[2], v3 = hp4[3];
    hv[0]=v0.x; hv[1]=v0.y; hv[2]=v0.z; hv[3]=v0.w;
    hv[4]=v1.x; hv[5]=v1.y; hv[6]=v1.z; hv[7]=v1.w;
    hv[8]=v2.x; hv[9]=v2.y; hv[10]=v2.z; hv[11]=v2.w;
    hv[12]=v3.x; hv[13]=v3.y; hv[14]=v3.z; hv[15]=v3.w;
    const float4* yp4 = reinterpret_cast<const float4*>(ysh + (size_t)e*16);
    float4 y0 = yp4[0], y1 = yp4[1], y2 = yp4[2], y3 = yp4[3];
    yv[0]=y0.x; yv[1]=y0.y; yv[2]=y0.z; yv[3]=y0.w;
    yv[4]=y1.x; yv[5]=y1.y; yv[6]=y1.z; yv[7]=y1.w;
    yv[8]=y2.x; yv[9]=y2.y; yv[10]=y2.z; yv[11]=y2.w;
    yv[12]=y3.x; yv[13]=y3.y; yv[14]=y3.z; yv[15]=y3.w;
    const unsigned short* rp = stg + (size_t)sidx*RWN + f;
    #pragma unroll
    for (int p = 0; p < NPATHS; p++) {
        uint32_t b = ((uint32_t)rp[p*64]) << 16;
        __builtin_memcpy(&rw[p], &b, 4);
    }
}

__global__ __launch_bounds__(256) void mace_gather_kernel(
    const float* __restrict__ h1,            // N*F*16
    const float* __restrict__ ysh,           // E*16
    const unsigned short* __restrict__ stg,  // STGCAP x 1472 bf16
    const int* __restrict__ senders,
    const int* __restrict__ offs,
    const int* __restrict__ eidx,
    int cb,
    float* __restrict__ out)                 // N*F*16
{
    int n = cb + blockIdx.x;
    int wv = threadIdx.x >> 6;
    int f  = threadIdx.x & 63;
    __shared__ float red[16][NWAVE*64];

    float acc[16];
    #pragma unroll
    for (int k = 0; k < 16; k++) acc[k] = 0.f;

    int coff0 = offs[cb];
    int ib = offs[n], ie = offs[n+1];
    int iecap = coff0 + STGCAP;
    if (ie > iecap) ie = iecap;              // same semantics as old break

    int i0 = ib + wv;
    int e0 = 0, s0 = 0, e1 = 0, s1 = 0;
    float hv0[16], yv0[16], rw0[23];

    if (i0 < ie) { e0 = eidx[i0]; s0 = senders[e0]; }
    if (i0 + NWAVE < ie) { e1 = eidx[i0 + NWAVE]; s1 = senders[e1]; }
    if (i0 < ie)
        gather_load(h1, ysh, stg, s0, e0, i0 - coff0, f, hv0, yv0, rw0);

    for (int idx = i0; idx < ie; ) {
        int nidx = idx + NWAVE;

        // issue next iteration's data loads (overlap with SALLP below)
        float hv1[16], yv1[16], rw1[23];
        if (nidx < ie)
            gather_load(h1, ysh, stg, s1, e1, nidx - coff0, f, hv1, yv1, rw1);

        // depth-2 index prefetch
        int e2 = 0, s2 = 0;
        int n2 = nidx + NWAVE;
        if (n2 < ie) { e2 = eidx[n2]; s2 = senders[e2]; }

        SALLP(hv0, yv0, rw0, acc)

        idx = nidx;
        e0 = e1; s0 = s1; e1 = e2; s1 = s2;
        #pragma unroll
        for (int k = 0; k < 16; k++) { hv0[k] = hv1[k]; yv0[k] = yv1[k]; }
        #pragma unroll
        for (int p = 0; p < NPATHS; p++) rw0[p] = rw1[p];
    }

    #pragma unroll
    for (int k = 0; k < 16; k++) red[k][wv*64 + f] = acc[k];
    __syncthreads();
    if (wv == 0) {
        float* dst = out + (size_t)n*1024 + f*16;
        #pragma unroll
        for (int k = 0; k < 16; k++) {
            float v = 0.f;
            #pragma unroll
            for (int w = 0; w < NWAVE; w++) v += red[k][w*64 + f];
            dst[k] = v;
        }
    }
}

// ---------------------------------------------------------------------------
// Fused symmetric product B2+B3 (sparse literal coefficients, registers only)
// ---------------------------------------------------------------------------

__global__ __launch_bounds__(256) void mace_prod_kernel(
    const float* __restrict__ A,       // N*F*16
    const float* __restrict__ w1base,  // S x 64
    const float* __restrict__ w2base,  // S x 23 x 64
    const float* __restrict__ w3base,  // S x 23 x 64
    const int* __restrict__ spec,
    float* __restrict__ out)           // N*F*16
{
    int gid = blockIdx.x * 256 + threadIdx.x;
    int n = gid >> 6, f = gid & 63;

    float a[16];
    {
        const float4* ap = reinterpret_cast<const float4*>(A + (size_t)n*1024 + f*16);
        float4 v0 = ap[0], v1 = ap[1], v2 = ap[2], v3 = ap[3];
        a[0]=v0.x; a[1]=v0.y; a[2]=v0.z; a[3]=v0.w;
        a[4]=v1.x; a[5]=v1.y; a[6]=v1.z; a[7]=v1.w;
        a[8]=v2.x; a[9]=v2.y; a[10]=v2.z; a[11]=v2.w;
        a[12]=v3.x; a[13]=v3.y; a[14]=v3.z; a[15]=v3.w;
    }
    int sp = spec[n];

    float wk[23];
    {
        const float* wp = w2base + (size_t)sp*(NPATHS*64) + f;
        #pragma unroll
        for (int p = 0; p < NPATHS; p++) wk[p] = wp[p*64];
    }
    float b2[16];
    #pragma unroll
    for (int k = 0; k < 16; k++) b2[k] = 0.f;
    SALLP(a, a, wk, b2)

    {
        const float* wp = w3base + (size_t)sp*(NPATHS*64) + f;
        #pragma unroll
        for (int p = 0; p < NPATHS; p++) wk[p] = wp[p*64];
    }
    float b3[16];
    #pragma unroll
    for (int k = 0; k < 16; k++) b3[k] = 0.f;
    SALLP(b2, a, wk, b3)

    float w1 = w1base[sp*64 + f];
    float4* dst4 = reinterpret_cast<float4*>(out + (size_t)n*1024 + f*16);
    float o[16];
    #pragma unroll
    for (int k = 0; k < 16; k++) o[k] = fmaf(a[k], w1, b2[k] + b3[k]);
    dst4[0] = make_float4(o[0], o[1], o[2], o[3]);
    dst4[1] = make_float4(o[4], o[5], o[6], o[7]);
    dst4[2] = make_float4(o[8], o[9], o[10], o[11]);
    dst4[3] = make_float4(o[12], o[13], o[14], o[15]);
}

// ---------------------------------------------------------------------------
// Readouts
// ---------------------------------------------------------------------------

__global__ void mace_readout0_kernel(const float* __restrict__ h,
                                     const float* __restrict__ roW,
                                     float* __restrict__ out)
{
    int n = blockIdx.x;
    int f = threadIdx.x;
    float v = h[(size_t)n*1024 + f*16] * roW[f];
    #pragma unroll
    for (int o = 32; o > 0; o >>= 1) v += __shfl_down(v, o, 64);
    if (f == 0) out[n] = v;
}

__global__ void mace_readout1_kernel(const float* __restrict__ h,
                                     const float* __restrict__ W1,
                                     const float* __restrict__ W2,
                                     float* __restrict__ out)
{
    int n = blockIdx.x;
    int f = threadIdx.x;
    __shared__ float sx[64];
    __shared__ float sz[16];
    sx[f] = h[(size_t)n*1024 + f*16];
    __syncthreads();
    if (f < 16) {
        float z = 0.f;
        #pragma unroll
        for (int g = 0; g < 64; g++) z = fmaf(sx[g], W1[g*16 + f], z);
        z = z / (1.f + expf(-z));
        sz[f] = z * W2[f];
    }
    __syncthreads();
    if (f == 0) {
        float t = 0.f;
        #pragma unroll
        for (int j = 0; j < 16; j++) t += sz[j];
        out[n] += t;
    }
}

// ---------------------------------------------------------------------------
// kernel_launch
// ---------------------------------------------------------------------------

extern "C" void kernel_launch(void* const* d_in, const int* in_sizes, int n_in,
                              void* d_out, int out_size, void* d_ws, size_t ws_size,
                              hipStream_t stream)
{
    const float* vectors = (const float*)d_in[0];
    const int*   senders = (const int*)d_in[1];
    const int*   receivers = (const int*)d_in[2];
    const int*   spec    = (const int*)d_in[3];
    const float* embed_W = (const float*)d_in[4];
    const float* skip_W  = (const float*)d_in[5];
    const float* lin1_W  = (const float*)d_in[6];
    const float* radW1   = (const float*)d_in[7];
    const float* radW2   = (const float*)d_in[8];
    const float* lin2_W  = (const float*)d_in[9];
    const float* skipf_W = (const float*)d_in[10];
    const float* prodW1  = (const float*)d_in[11];
    const float* prodW2  = (const float*)d_in[12];
    const float* prodW3  = (const float*)d_in[13];
    const float* plin_W  = (const float*)d_in[14];
    const float* ro_W    = (const float*)d_in[15];
    const float* mlp_W1  = (const float*)d_in[16];
    const float* mlp_W2  = (const float*)d_in[17];
    float* out = (float*)d_out;

    // workspace layout (floats); ~124 MB (round-16-proven layout).
    float* w   = (float*)d_ws;
    float* ysh = w;                              // E*16
    float* rbf = ysh + (size_t)NEDGE * 16;       // E*8
    float* hid = rbf + (size_t)NEDGE * 8;        // E*64 region (bf16 uses half)
    float* t0  = hid + (size_t)NEDGE * 64;       // h1 input (live in gather)
    float* t1  = t0 + NF16;                      // gather output
    float* sc  = t1 + NF16;                      // skip (layer 1)
    float* h   = sc + NF16;                      // node state / staging lo
    float* t2  = h  + NF16;                      // staging mid
    float* ext = t2 + NF16;                      // staging hi / Wc (epilogue)
    unsigned short* hidb = (unsigned short*)hid; // E*64 bf16
    unsigned short* stg = (unsigned short*)h;    // STGCAP*1472 bf16
    float* wc  = ext;                            // composed weights, 10*4*64*64
    unsigned short* wt = (unsigned short*)(ext + NF16);  // W2t bf16, 94208
    int* cnt  = (int*)((char*)wt + (size_t)RWN*64*2);    // 4096 (16B-aligned)
    int* offs = cnt + 4096;                      // 4097
    int* cur  = offs + 4097;                     // 4096
    int* eidx = cur + 4096;                      // 65536
    int* scnt  = eidx + NEDGE;                   // 16
    int* scur  = scnt + 16;                      // 16
    int* snode = scur + 16;                      // 4096

    const float EPS = 0.24253562503633297f;   // 1/sqrt(1+16)

    // CSR build (edges by receiver)
    (void)hipMemsetAsync(cnt, 0, 4096 * sizeof(int), stream);
    csr_hist_kernel<<<NEDGE/256, 256, 0, stream>>>(receivers, cnt);
    csr_scan_kernel<<<1, 1024, 0, stream>>>(cnt, offs, cur);
    csr_scatter_kernel<<<NEDGE/256, 256, 0, stream>>>(receivers, cur, eidx);

    // species sort (nodes by species)
    (void)hipMemsetAsync(scnt, 0, 32 * sizeof(int), stream);
    sp_hist_kernel<<<NNODE/256, 256, 0, stream>>>(spec, scnt);
    sp_scan_kernel<<<1, 64, 0, stream>>>(scnt, scur);
    sp_scatter_kernel<<<NNODE/256, 256, 0, stream>>>(spec, scur, snode);

    mace_geom_kernel<<<NEDGE/256, 256, 0, stream>>>(vectors, ysh, rbf);
    mace_init_h_kernel<<<(NNODE*1024)/256, 256, 0, stream>>>(spec, embed_W, h);

    dim3 ggrid((STGCAP + 63)/64, NPATHS);

    for (int layer = 0; layer < 2; layer++) {
        const float* W1 = radW1 + (size_t)layer * 8 * HDIM;
        const float* W2 = radW2 + (size_t)layer * HDIM * RWN;
        const float* l1W = lin1_W + (size_t)layer * 4 * FDIM * FDIM;
        const float* l2W = lin2_W + (size_t)layer * 4 * FDIM * FDIM;
        const float* plW = plin_W + (size_t)layer * 4 * FDIM * FDIM;
        const float* pw1 = prodW1 + (size_t)layer * NSPEC * FDIM;
        const float* pw2 = prodW2 + (size_t)layer * NSPEC * NPATHS * FDIM;
        const float* pw3 = prodW3 + (size_t)layer * NSPEC * NPATHS * FDIM;

        if (layer == 1) {
            mace_lin_sp_kernel<<<NNODE/LINB, 512, 0, stream>>>(
                h, skip_W + (size_t)1 * NSPEC * 4 * FDIM * FDIM, spec, snode,
                nullptr, sc);
        }

        mace_radial_kernel<<<(NEDGE*HDIM)/256, 256, 0, stream>>>(rbf, W1, hidb);
        w2t_kernel<<<(RWN*64 + 255)/256, 256, 0, stream>>>(W2, wt);
        mace_lin_kernel<<<NNODE/LINB, 512, 0, stream>>>(h, l1W, nullptr, t0, 1.0f);
        // h/t2/ext dead from here until after the chunk loop

        for (int c = 0; c < NCHUNK; c++) {
            int cb = c * CHUNKN;
            rw_gemm_chunk<<<ggrid, 256, 0, stream>>>(hidb, wt, offs, eidx, cb, stg);
            mace_gather_kernel<<<CHUNKN, 256, 0, stream>>>(
                t0, ysh, stg, senders, offs, eidx, cb, t1);
        }

        if (layer == 0) {
            compose_kernel<<<(NSPEC*4*64*64)/256, 256, 0, stream>>>(skipf_W, l2W, wc, EPS);
            mace_lin_sp_kernel<<<NNODE/LINB, 512, 0, stream>>>(
                t1, wc, spec, snode, nullptr, h);
            mace_prod_kernel<<<NNODE/4, 256, 0, stream>>>(h, pw1, pw2, pw3, spec, t1);
            mace_lin_kernel<<<NNODE/LINB, 512, 0, stream>>>(t1, plW, nullptr, h, 1.0f);
            mace_readout0_kernel<<<NNODE, 64, 0, stream>>>(h, ro_W, out);
        } else {
            mace_lin_kernel<<<NNODE/LINB, 512, 0, stream>>>(t1, l2W, nullptr, t2, EPS);
            mace_prod_kernel<<<NNODE/4, 256, 0, stream>>>(t2, pw1, pw2, pw3, spec, t1);
            mace_lin_kernel<<<NNODE/LINB, 512, 0, stream>>>(t1, plW, sc, t0, 1.0f);
            mace_readout1_kernel<<<NNODE, 64, 0, stream>>>(t0, mlp_W1, mlp_W2, out);
        }
    }
}

// Round 18
// 956.101 us; speedup vs baseline: 1.2124x; 1.2124x over previous
//
#include <hip/hip_runtime.h>
#include <cstdint>
#include <cstring>
#include <cmath>

#define NEDGE 65536
#define NNODE 4096
#define FDIM  64
#define LMDIM 16
#define NPATHS 23
#define HDIM  64
#define NSPEC 10
#define RWN   (NPATHS*FDIM)                    // 1472
#define NF16  ((size_t)NNODE * FDIM * LMDIM)   // 4,194,304 floats
#define STGCAP 17088                           // staged edges per chunk
#define CHUNKN 1024                            // nodes per chunk
#define NCHUNK (NNODE/CHUNKN)                  // 4
#define NWAVE 4                                // waves per gather block
#define LINB  8                                // nodes per lin block

typedef __attribute__((ext_vector_type(8))) short bf16x8;
typedef __attribute__((ext_vector_type(4))) float f32x4;

__device__ __forceinline__ unsigned short f32_to_bf16_rne(float v)
{
    uint32_t bits;
    __builtin_memcpy(&bits, &v, 4);
    bits += 0x7fffu + ((bits >> 16) & 1u);
    return (unsigned short)(bits >> 16);
}

// ===========================================================================
// Compile-time Clebsch-Gordan coefficients (constexpr; no device tables)
// ===========================================================================

struct cxd { double re, im; };
constexpr cxd cmul_(cxd a, cxd b){ return {a.re*b.re - a.im*b.im, a.re*b.im + a.im*b.re}; }
constexpr cxd cadd_(cxd a, cxd b){ return {a.re + b.re, a.im + b.im}; }

constexpr double csqrt_(double x)
{
    if (x <= 0.0) return 0.0;
    double g = (x < 1.0) ? 1.0 : x;
    for (int i = 0; i < 30; i++) g = 0.5*(g + x/g);
    return g;
}

constexpr double su2_c_(int j1, int j2, int j3, int m1, int m2, int m3,
                        const double* F)
{
    if (m1 + m2 != m3) return 0.0;
    int vmin = -j1 + j2 + m3; if (-j1 + m1 > vmin) vmin = -j1 + m1; if (vmin < 0) vmin = 0;
    int vmax = j2 + j3 + m1; if (j3 - j1 + j2 < vmax) vmax = j3 - j1 + j2; if (j3 + m3 < vmax) vmax = j3 + m3;
    double C = csqrt_((2.0*j3 + 1.0) * F[j3+j1-j2] * F[j3-j1+j2] * F[j1+j2-j3] / F[j1+j2+j3+1])
             * csqrt_(F[j3+m3] * F[j3-m3] / (F[j1-m1] * F[j1+m1] * F[j2-m2] * F[j2+m2]));
    double S = 0.0;
    for (int v = vmin; v <= vmax; v++) {
        double t = F[j2+j3+m1-v] * F[j1-m1+v]
                 / (F[v] * F[j3-j1+j2-v] * F[j3+m3-v] * F[v+j1-j2-m3]);
        S += (((v + j2 + m2) & 1) ? -1.0 : 1.0) * t;
    }
    return C * S;
}

struct QM { cxd q[7][7]; };

constexpr QM qmat_c_(int l)
{
    QM Q{};
    double is2 = 1.0 / csqrt_(2.0);
    for (int m = -l; m < 0; m++) {
        Q.q[l+m][l-m] = cxd{is2, 0.0};
        Q.q[l+m][l+m] = cxd{0.0, -is2};
    }
    Q.q[l][l] = cxd{1.0, 0.0};
    for (int m = 1; m <= l; m++) {
        double s = (m & 1) ? -1.0 : 1.0;
        Q.q[l+m][l+m] = cxd{s*is2, 0.0};
        Q.q[l+m][l-m] = cxd{0.0, s*is2};
    }
    cxd ph = (l==0) ? cxd{1,0} : (l==1) ? cxd{0,-1} : (l==2) ? cxd{-1,0} : cxd{0,1};
    for (int a = 0; a < 7; a++)
        for (int b = 0; b < 7; b++)
            Q.q[a][b] = cmul_(Q.q[a][b], ph);
    return Q;
}

template<int L1, int L2, int L3>
struct CGPath { float v[(2*L1+1)*(2*L2+1)*(2*L3+1)]; };

template<int L1, int L2, int L3>
constexpr CGPath<L1,L2,L3> make_path_()
{
    constexpr int d1 = 2*L1+1, d2 = 2*L2+1, d3 = 2*L3+1;
    CGPath<L1,L2,L3> R{};
    double F[16] = {};
    F[0] = 1.0;
    for (int i = 1; i < 16; i++) F[i] = F[i-1] * i;
    QM q1 = qmat_c_(L1), q2 = qmat_c_(L2), q3 = qmat_c_(L3);
    double Cc[7][7][7] = {};
    for (int i = 0; i < d1; i++)
    for (int k = 0; k < d2; k++)
    for (int m = 0; m < d3; m++)
        Cc[i][k][m] = su2_c_(L1, L2, L3, i-L1, k-L2, m-L3, F);
    for (int jj = 0; jj < d1; jj++)
    for (int bb = 0; bb < d2; bb++)
    for (int cc = 0; cc < d3; cc++) {
        cxd s{0.0, 0.0};
        for (int i = 0; i < d1; i++) {
            cxd a = q1.q[i][jj];
            if (a.re == 0.0 && a.im == 0.0) continue;
            for (int k = 0; k < d2; k++) {
                cxd b = q2.q[k][bb];
                if (b.re == 0.0 && b.im == 0.0) continue;
                for (int m = 0; m < d3; m++) {
                    cxd g = q3.q[m][cc];
                    if (g.re == 0.0 && g.im == 0.0) continue;
                    double cg = Cc[i][k][m];
                    if (cg == 0.0) continue;
                    cxd gc = {g.re*cg, -g.im*cg};   // conj(q3)*cg
                    s = cadd_(s, cmul_(cmul_(a, b), gc));
                }
            }
        }
        R.v[(jj*d2 + bb)*d3 + cc] = (float)s.re;
    }
    return R;
}

// compile-time loop helper
template<int V> struct ic_ { static constexpr int value = V; };
template<int I, int N, typename F>
__device__ __forceinline__ void cfor_(F& f)
{
    if constexpr (I < N) { f(ic_<I>{}); cfor_<I+1, N>(f); }
}
template<int N, typename F>
__device__ __forceinline__ void cfor(F f) { cfor_<0, N>(f); }

// Sparse CG contraction with literal coefficients
template<int L1, int L2, int L3>
__device__ __forceinline__ void spath(const float* __restrict__ a1,
                                      const float* __restrict__ a2,
                                      float w, float* __restrict__ acc)
{
    constexpr CGPath<L1,L2,L3> P = make_path_<L1,L2,L3>();
    constexpr int d2 = 2*L2+1, d3 = 2*L3+1;
    float t[d3];
    #pragma unroll
    for (int k = 0; k < d3; k++) t[k] = 0.f;
    cfor<2*L1+1>([&](auto I) {
        cfor<d2>([&](auto J) {
            constexpr int i = decltype(I)::value;
            constexpr int j = decltype(J)::value;
            float pr = a1[i] * a2[j];
            (void)pr;
            cfor<d3>([&](auto K) {
                constexpr int k = decltype(K)::value;
                constexpr float c = P.v[(i*d2 + j)*d3 + k];
                if constexpr (c > 1e-10f || c < -1e-10f)
                    t[k] = fmaf(c, pr, t[k]);
            });
        });
    });
    #pragma unroll
    for (int k = 0; k < d3; k++) acc[k] = fmaf(w, t[k], acc[k]);
}

#define SALLP(A1, A2, W, ACC)                       \
    spath<0,0,0>(A1+0, A2+0, (W)[ 0], ACC+0);       \
    spath<0,1,1>(A1+0, A2+1, (W)[ 1], ACC+1);       \
    spath<0,2,2>(A1+0, A2+4, (W)[ 2], ACC+4);       \
    spath<0,3,3>(A1+0, A2+9, (W)[ 3], ACC+9);       \
    spath<1,0,1>(A1+1, A2+0, (W)[ 4], ACC+1);       \
    spath<1,1,0>(A1+1, A2+1, (W)[ 5], ACC+0);       \
    spath<1,1,2>(A1+1, A2+1, (W)[ 6], ACC+4);       \
    spath<1,2,1>(A1+1, A2+4, (W)[ 7], ACC+1);       \
    spath<1,2,3>(A1+1, A2+4, (W)[ 8], ACC+9);       \
    spath<1,3,2>(A1+1, A2+9, (W)[ 9], ACC+4);       \
    spath<2,0,2>(A1+4, A2+0, (W)[10], ACC+4);       \
    spath<2,1,1>(A1+4, A2+1, (W)[11], ACC+1);       \
    spath<2,1,3>(A1+4, A2+1, (W)[12], ACC+9);       \
    spath<2,2,0>(A1+4, A2+4, (W)[13], ACC+0);       \
    spath<2,2,2>(A1+4, A2+4, (W)[14], ACC+4);       \
    spath<2,3,1>(A1+4, A2+9, (W)[15], ACC+1);       \
    spath<2,3,3>(A1+4, A2+9, (W)[16], ACC+9);       \
    spath<3,0,3>(A1+9, A2+0, (W)[17], ACC+9);       \
    spath<3,1,2>(A1+9, A2+1, (W)[18], ACC+4);       \
    spath<3,2,1>(A1+9, A2+4, (W)[19], ACC+1);       \
    spath<3,2,3>(A1+9, A2+4, (W)[20], ACC+9);       \
    spath<3,3,0>(A1+9, A2+9, (W)[21], ACC+0);       \
    spath<3,3,2>(A1+9, A2+9, (W)[22], ACC+4);

// ---------------------------------------------------------------------------
// Geometry
// ---------------------------------------------------------------------------

__global__ void mace_geom_kernel(const float* __restrict__ vec,
                                 float* __restrict__ ysh, float* __restrict__ rbf)
{
    int e = blockIdx.x * blockDim.x + threadIdx.x;
    if (e >= NEDGE) return;
    float x = vec[3*e+0], y = vec[3*e+1], z = vec[3*e+2];
    float r = sqrtf(x*x + y*y + z*z);
    float inv = 1.0f / (r + 1e-9f);
    float ux = x*inv, uy = y*inv, uz = z*inv;

    const float s3    = 1.7320508075688772f;
    const float s5_2  = 1.1180339887498949f;
    const float s15   = 3.8729833462074170f;
    const float s15_2 = 1.9364916731037085f;
    const float s35_8 = 2.0916500663351889f;
    const float s105  = 10.246950765959598f;
    const float s21_8 = 1.6201851746019651f;
    const float s7_2  = 1.3228756555322954f;
    const float s105_2= 5.1234753829797990f;

    float* Y = ysh + (size_t)e * 16;
    Y[0]  = 1.0f;
    Y[1]  = s3 * uy;
    Y[2]  = s3 * uz;
    Y[3]  = s3 * ux;
    Y[4]  = s15 * ux * uy;
    Y[5]  = s15 * uy * uz;
    Y[6]  = s5_2 * (3.f*uz*uz - 1.f);
    Y[7]  = s15 * ux * uz;
    Y[8]  = s15_2 * (ux*ux - uy*uy);
    Y[9]  = s35_8 * uy * (3.f*ux*ux - uy*uy);
    Y[10] = s105 * ux * uy * uz;
    Y[11] = s21_8 * uy * (5.f*uz*uz - 1.f);
    Y[12] = s7_2 * uz * (5.f*uz*uz - 3.f);
    Y[13] = s21_8 * ux * (5.f*uz*uz - 1.f);
    Y[14] = s105_2 * uz * (ux*ux - uy*uy);
    Y[15] = s35_8 * ux * (ux*ux - 3.f*uy*uy);

    float env = 0.f;
    if (r < 1.f) {
        float r2 = r*r, r3 = r2*r, r6 = r3*r3, r7 = r6*r, r8 = r7*r;
        env = 1.f - 28.f*r6 + 48.f*r7 - 21.f*r8;
    }
    const float sq2 = 1.4142135623730951f;
    const float PI_ = 3.14159265358979323846f;
    float* R = rbf + (size_t)e * 8;
    #pragma unroll
    for (int n = 1; n <= 8; n++)
        R[n-1] = sq2 * sinf(PI_ * (float)n * r) * inv * env;
}

__global__ void mace_init_h_kernel(const int* __restrict__ spec,
                                   const float* __restrict__ embed,
                                   float* __restrict__ h)
{
    int idx = blockIdx.x * blockDim.x + threadIdx.x;
    int n = idx >> 10;
    int t = idx & 1023;
    int f = t >> 4, m = t & 15;
    h[idx] = (m == 0) ? embed[spec[n]*FDIM + f] : 0.f;
}

// radial: silu(rbf @ W1) -> bf16 directly (GEMM input)
__global__ void mace_radial_kernel(const float* __restrict__ rbf,
                                   const float* __restrict__ W1,
                                   unsigned short* __restrict__ hidb)
{
    int idx = blockIdx.x * blockDim.x + threadIdx.x;   // NEDGE*64
    int e = idx >> 6, j = idx & 63;
    float a = 0.f;
    #pragma unroll
    for (int n = 0; n < 8; n++)
        a = fmaf(rbf[(size_t)e*8 + n], W1[n*64 + j], a);
    hidb[idx] = f32_to_bf16_rne(a / (1.f + expf(-a)));
}

// W2t[n][h] bf16 = W2[h][n]
__global__ void w2t_kernel(const float* __restrict__ W2,
                           unsigned short* __restrict__ w2t)
{
    int idx = blockIdx.x * blockDim.x + threadIdx.x;   // RWN*64
    if (idx >= RWN*64) return;
    int h = idx & 63, n = idx >> 6;
    w2t[idx] = f32_to_bf16_rne(W2[(size_t)h*RWN + n]);
}

// ---------------------------------------------------------------------------
// CSR build (edges by receiver) + species sort (nodes by species)
// ---------------------------------------------------------------------------

__global__ void csr_hist_kernel(const int* __restrict__ recv, int* __restrict__ cnt)
{
    int e = blockIdx.x * blockDim.x + threadIdx.x;
    if (e < NEDGE) atomicAdd(&cnt[recv[e]], 1);
}

__global__ void csr_scan_kernel(const int* __restrict__ cnt,
                                int* __restrict__ off, int* __restrict__ cur)
{
    __shared__ int part[1024];
    int t = threadIdx.x;
    int v0 = cnt[t*4+0], v1 = cnt[t*4+1], v2 = cnt[t*4+2], v3 = cnt[t*4+3];
    int sum = v0 + v1 + v2 + v3;
    part[t] = sum;
    __syncthreads();
    for (int d = 1; d < 1024; d <<= 1) {
        int x = (t >= d) ? part[t-d] : 0;
        __syncthreads();
        part[t] += x;
        __syncthreads();
    }
    int run = part[t] - sum;
    off[t*4+0] = run; cur[t*4+0] = run; run += v0;
    off[t*4+1] = run; cur[t*4+1] = run; run += v1;
    off[t*4+2] = run; cur[t*4+2] = run; run += v2;
    off[t*4+3] = run; cur[t*4+3] = run; run += v3;
    if (t == 1023) off[4096] = run;
}

__global__ void csr_scatter_kernel(const int* __restrict__ recv,
                                   int* __restrict__ cur, int* __restrict__ eidx)
{
    int e = blockIdx.x * blockDim.x + threadIdx.x;
    if (e < NEDGE) {
        int pos = atomicAdd(&cur[recv[e]], 1);
        eidx[pos] = e;
    }
}

__global__ void sp_hist_kernel(const int* __restrict__ spec, int* __restrict__ scnt)
{
    int n = blockIdx.x * blockDim.x + threadIdx.x;
    if (n < NNODE) atomicAdd(&scnt[spec[n]], 1);
}

__global__ void sp_scan_kernel(const int* __restrict__ scnt, int* __restrict__ scur)
{
    if (threadIdx.x == 0) {
        int run = 0;
        for (int s = 0; s < NSPEC; s++) { scur[s] = run; run += scnt[s]; }
    }
}

__global__ void sp_scatter_kernel(const int* __restrict__ spec,
                                  int* __restrict__ scur, int* __restrict__ snode)
{
    int n = blockIdx.x * blockDim.x + threadIdx.x;
    if (n < NNODE) {
        int pos = atomicAdd(&scur[spec[n]], 1);
        snode[pos] = n;
    }
}

// ---------------------------------------------------------------------------
// Chunked Rw GEMM via MFMA (bf16 in, bf16 out). LDS-staged output tile so
// global stores are contiguous 128B rows (MFMA D layout scatters 32B).
// ---------------------------------------------------------------------------

__global__ __launch_bounds__(256) void rw_gemm_chunk(
    const unsigned short* __restrict__ hidb,  // E x 64 bf16
    const unsigned short* __restrict__ w2t,   // 1472 x 64 bf16
    const int* __restrict__ offs,
    const int* __restrict__ eidx,
    int cb,
    unsigned short* __restrict__ stg)         // STGCAP x 1472 bf16
{
    __shared__ __align__(16) unsigned short sout[64][72];  // pad 72: 16B-aligned rows
    int coff0 = offs[cb];
    int count = offs[cb + CHUNKN] - coff0;
    if (count > STGCAP) count = STGCAP;
    int e0 = blockIdx.x * 64;                 // edge base (N)
    if (e0 >= count) return;
    int n0 = blockIdx.y * 64;                 // w2-col base (M)
    int wv = threadIdx.x >> 6;                // m-strip 0..3
    int l  = threadIdx.x & 63;
    int lm = l & 15, q = l >> 4;

    const unsigned short* arow = w2t + (size_t)(n0 + wv*16 + lm) * 64 + q*8;
    bf16x8 a0 = *reinterpret_cast<const bf16x8*>(arow);
    bf16x8 a1 = *reinterpret_cast<const bf16x8*>(arow + 32);

    f32x4 acc[4];
    int erow[4];
    #pragma unroll
    for (int t = 0; t < 4; t++) {
        int row = e0 + t*16 + lm;
        erow[t] = eidx[coff0 + ((row < count) ? row : 0)];
        acc[t] = (f32x4){0.f, 0.f, 0.f, 0.f};
    }
    #pragma unroll
    for (int t = 0; t < 4; t++) {
        const unsigned short* brow = hidb + (size_t)erow[t] * 64 + q*8;
        bf16x8 b0 = *reinterpret_cast<const bf16x8*>(brow);
        bf16x8 b1 = *reinterpret_cast<const bf16x8*>(brow + 32);
        acc[t] = __builtin_amdgcn_mfma_f32_16x16x32_bf16(a0, b0, acc[t], 0, 0, 0);
        acc[t] = __builtin_amdgcn_mfma_f32_16x16x32_bf16(a1, b1, acc[t], 0, 0, 0);
    }

    // stage D tile in LDS (row = edge index within tile, col = w2 col)
    #pragma unroll
    for (int t = 0; t < 4; t++) {
        unsigned short u[4];
        u[0] = f32_to_bf16_rne(acc[t][0]);
        u[1] = f32_to_bf16_rne(acc[t][1]);
        u[2] = f32_to_bf16_rne(acc[t][2]);
        u[3] = f32_to_bf16_rne(acc[t][3]);
        uint2 pack;
        pack.x = (uint32_t)u[0] | ((uint32_t)u[1] << 16);
        pack.y = (uint32_t)u[2] | ((uint32_t)u[3] << 16);
        *reinterpret_cast<uint2*>(&sout[t*16 + lm][wv*16 + q*4]) = pack;
    }
    __syncthreads();

    // cooperative coalesced store: 64 rows x 128B; 8 lanes cover one row
    #pragma unroll
    for (int r2 = 0; r2 < 2; r2++) {
        int idx = r2*256 + threadIdx.x;   // 0..511
        int row = idx >> 3;               // 0..63
        int seg = idx & 7;                // 0..7 (16B each)
        if (e0 + row < count) {
            *reinterpret_cast<uint4*>(&stg[(size_t)(e0+row)*RWN + n0 + seg*8]) =
                *reinterpret_cast<const uint4*>(&sout[row][seg*8]);
        }
    }
}

// ---------------------------------------------------------------------------
// Batched shared-weight lin: LINB nodes per block, weights register-resident.
// ---------------------------------------------------------------------------

__global__ __launch_bounds__(512, 2) void mace_lin_kernel(
    const float* __restrict__ in, const float* __restrict__ W,
    const float* __restrict__ add, float* __restrict__ out, float scale)
{
    __shared__ __align__(16) float st[LINB][16*68];
    int nb = blockIdx.x * LINB;
    int tid = threadIdx.x;

    #pragma unroll
    for (int j = 0; j < LINB; j++) {
        size_t base = (size_t)(nb + j) * 1024;
        float2 v = *reinterpret_cast<const float2*>(in + base + tid*2);
        int f = tid >> 3;
        int m = (tid & 7) * 2;
        st[j][m*68 + f]     = v.x;
        st[j][(m+1)*68 + f] = v.y;
    }
    __syncthreads();

    int fp = tid >> 4;          // 0..31
    int m  = tid & 15;
    int l  = (m == 0) ? 0 : (m < 4) ? 1 : (m < 9) ? 2 : 3;
    const float* Wl = W + l*4096;
    int f0 = fp * 2;

    float4 wa[16], wb[16];
    #pragma unroll
    for (int q = 0; q < 16; q++) {
        wa[q] = *reinterpret_cast<const float4*>(Wl + (size_t)f0*64 + q*4);
        wb[q] = *reinterpret_cast<const float4*>(Wl + (size_t)(f0+1)*64 + q*4);
    }

    #pragma unroll
    for (int j = 0; j < LINB; j++) {
        float ax = 0.f, ay = 0.f, az = 0.f, aw = 0.f;
        float bx = 0.f, by = 0.f, bz = 0.f, bw = 0.f;
        #pragma unroll
        for (int q = 0; q < 16; q++) {
            float4 sv = *reinterpret_cast<const float4*>(&st[j][m*68 + q*4]);
            ax = fmaf(wa[q].x, sv.x, ax); ay = fmaf(wa[q].y, sv.y, ay);
            az = fmaf(wa[q].z, sv.z, az); aw = fmaf(wa[q].w, sv.w, aw);
            bx = fmaf(wb[q].x, sv.x, bx); by = fmaf(wb[q].y, sv.y, by);
            bz = fmaf(wb[q].z, sv.z, bz); bw = fmaf(wb[q].w, sv.w, bw);
        }
        float a0 = ((ax + ay) + (az + aw)) * scale;
        float a1 = ((bx + by) + (bz + bw)) * scale;
        size_t o0 = (size_t)(nb + j) * 1024 + (size_t)f0*16 + m;
        if (add) { a0 += add[o0]; a1 += add[o0 + 16]; }
        out[o0] = a0;
        out[o0 + 16] = a1;
    }
}

// Species-sorted batched lin_sp
__global__ __launch_bounds__(512, 2) void mace_lin_sp_kernel(
    const float* __restrict__ in, const float* __restrict__ Wsp,
    const int* __restrict__ spec, const int* __restrict__ snode,
    const float* __restrict__ add, float* __restrict__ out)
{
    __shared__ __align__(16) float st[LINB][16*68];
    __shared__ int nodes[LINB];
    int nb = blockIdx.x * LINB;
    int tid = threadIdx.x;

    if (tid < LINB) nodes[tid] = snode[nb + tid];
    __syncthreads();

    #pragma unroll
    for (int j = 0; j < LINB; j++) {
        size_t base = (size_t)nodes[j] * 1024;
        float2 v = *reinterpret_cast<const float2*>(in + base + tid*2);
        int f = tid >> 3;
        int m = (tid & 7) * 2;
        st[j][m*68 + f]     = v.x;
        st[j][(m+1)*68 + f] = v.y;
    }
    __syncthreads();

    int fp = tid >> 4;
    int m  = tid & 15;
    int l  = (m == 0) ? 0 : (m < 4) ? 1 : (m < 9) ? 2 : 3;
    int f0 = fp * 2;

    int sp_cur = spec[nodes[0]];
    const float* Wl = Wsp + (size_t)sp_cur*4*4096 + l*4096;
    float4 wa[16], wb[16];
    #pragma unroll
    for (int q = 0; q < 16; q++) {
        wa[q] = *reinterpret_cast<const float4*>(Wl + (size_t)f0*64 + q*4);
        wb[q] = *reinterpret_cast<const float4*>(Wl + (size_t)(f0+1)*64 + q*4);
    }

    #pragma unroll
    for (int j = 0; j < LINB; j++) {
        int spj = spec[nodes[j]];
        if (spj != sp_cur) {
            sp_cur = spj;
            const float* Wl2 = Wsp + (size_t)sp_cur*4*4096 + l*4096;
            #pragma unroll
            for (int q = 0; q < 16; q++) {
                wa[q] = *reinterpret_cast<const float4*>(Wl2 + (size_t)f0*64 + q*4);
                wb[q] = *reinterpret_cast<const float4*>(Wl2 + (size_t)(f0+1)*64 + q*4);
            }
        }
        float ax = 0.f, ay = 0.f, az = 0.f, aw = 0.f;
        float bx = 0.f, by = 0.f, bz = 0.f, bw = 0.f;
        #pragma unroll
        for (int q = 0; q < 16; q++) {
            float4 sv = *reinterpret_cast<const float4*>(&st[j][m*68 + q*4]);
            ax = fmaf(wa[q].x, sv.x, ax); ay = fmaf(wa[q].y, sv.y, ay);
            az = fmaf(wa[q].z, sv.z, az); aw = fmaf(wa[q].w, sv.w, aw);
            bx = fmaf(wb[q].x, sv.x, bx); by = fmaf(wb[q].y, sv.y, by);
            bz = fmaf(wb[q].z, sv.z, bz); bw = fmaf(wb[q].w, sv.w, bw);
        }
        float a0 = (ax + ay) + (az + aw);
        float a1 = (bx + by) + (bz + bw);
        size_t o0 = (size_t)nodes[j] * 1024 + (size_t)f0*16 + m;
        if (add) { a0 += add[o0]; a1 += add[o0 + 16]; }
        out[o0] = a0;
        out[o0 + 16] = a1;
    }
}

// Compose Wc[sp][l][f][g] = eps * sum_k skipf[sp][l][f][k] * l2W[l][k][g]
__global__ __launch_bounds__(256) void compose_kernel(
    const float* __restrict__ skipf, const float* __restrict__ l2W,
    float* __restrict__ Wc, float eps)
{
    int idx = blockIdx.x * 256 + threadIdx.x;   // 10*4*64*64
    int g = idx & 63, f = (idx >> 6) & 63, l = (idx >> 12) & 3, sp = idx >> 14;
    const float* A = skipf + ((size_t)sp*4 + l)*4096 + f*64;
    const float* B = l2W + (size_t)l*4096 + g;
    float s0 = 0.f, s1 = 0.f;
    #pragma unroll 8
    for (int k = 0; k < 64; k += 2) {
        s0 = fmaf(A[k],   B[(size_t)k*64],        s0);
        s1 = fmaf(A[k+1], B[(size_t)(k+1)*64],    s1);
    }
    Wc[idx] = (s0 + s1) * eps;
}

// ---------------------------------------------------------------------------
// Message gather: round-16 proven form (4 waves per node, index prefetch)
// ---------------------------------------------------------------------------

__global__ __launch_bounds__(256) void mace_gather_kernel(
    const float* __restrict__ h1,            // N*F*16
    const float* __restrict__ ysh,           // E*16
    const unsigned short* __restrict__ stg,  // STGCAP x 1472 bf16
    const int* __restrict__ senders,
    const int* __restrict__ offs,
    const int* __restrict__ eidx,
    int cb,
    float* __restrict__ out)                 // N*F*16
{
    int n = cb + blockIdx.x;
    int wv = threadIdx.x >> 6;
    int f  = threadIdx.x & 63;
    __shared__ float red[16][NWAVE*64];

    float acc[16];
    #pragma unroll
    for (int k = 0; k < 16; k++) acc[k] = 0.f;

    int coff0 = offs[cb];
    int ib = offs[n], ie = offs[n+1];

    int idx = ib + wv;
    int e = 0, s = 0;
    if (idx < ie) { e = eidx[idx]; s = senders[e]; }

    for (; idx < ie; idx += NWAVE) {
        int sidx = idx - coff0;
        if (sidx >= STGCAP) break;
        int nidx = idx + NWAVE;
        int en = 0;
        if (nidx < ie) en = eidx[nidx];

        float hv[16];
        {
            const float4* hp4 = reinterpret_cast<const float4*>(
                h1 + (size_t)s*1024 + f*16);
            float4 v0 = hp4[0], v1 = hp4[1], v2 = hp4[2], v3 = hp4[3];
            hv[0]=v0.x; hv[1]=v0.y; hv[2]=v0.z; hv[3]=v0.w;
            hv[4]=v1.x; hv[5]=v1.y; hv[6]=v1.z; hv[7]=v1.w;
            hv[8]=v2.x; hv[9]=v2.y; hv[10]=v2.z; hv[11]=v2.w;
            hv[12]=v3.x; hv[13]=v3.y; hv[14]=v3.z; hv[15]=v3.w;
        }
        float yv[16];
        {
            const float4* yp4 = reinterpret_cast<const float4*>(ysh + (size_t)e*16);
            float4 v0 = yp4[0], v1 = yp4[1], v2 = yp4[2], v3 = yp4[3];
            yv[0]=v0.x; yv[1]=v0.y; yv[2]=v0.z; yv[3]=v0.w;
            yv[4]=v1.x; yv[5]=v1.y; yv[6]=v1.z; yv[7]=v1.w;
            yv[8]=v2.x; yv[9]=v2.y; yv[10]=v2.z; yv[11]=v2.w;
            yv[12]=v3.x; yv[13]=v3.y; yv[14]=v3.z; yv[15]=v3.w;
        }
        float rw[23];
        {
            const unsigned short* rp = stg + (size_t)sidx*RWN + f;
            #pragma unroll
            for (int p = 0; p < NPATHS; p++) {
                uint32_t b = ((uint32_t)rp[p*64]) << 16;
                __builtin_memcpy(&rw[p], &b, 4);
            }
        }
        int sn = 0;
        if (nidx < ie) sn = senders[en];

        SALLP(hv, yv, rw, acc)

        e = en; s = sn;
    }

    #pragma unroll
    for (int k = 0; k < 16; k++) red[k][wv*64 + f] = acc[k];
    __syncthreads();
    if (wv == 0) {
        float* dst = out + (size_t)n*1024 + f*16;
        #pragma unroll
        for (int k = 0; k < 16; k++) {
            float v = 0.f;
            #pragma unroll
            for (int w = 0; w < NWAVE; w++) v += red[k][w*64 + f];
            dst[k] = v;
        }
    }
}

// ---------------------------------------------------------------------------
// Fused symmetric product B2+B3 (sparse literal coefficients, registers only)
// ---------------------------------------------------------------------------

__global__ __launch_bounds__(256) void mace_prod_kernel(
    const float* __restrict__ A,       // N*F*16
    const float* __restrict__ w1base,  // S x 64
    const float* __restrict__ w2base,  // S x 23 x 64
    const float* __restrict__ w3base,  // S x 23 x 64
    const int* __restrict__ spec,
    float* __restrict__ out)           // N*F*16
{
    int gid = blockIdx.x * 256 + threadIdx.x;
    int n = gid >> 6, f = gid & 63;

    float a[16];
    {
        const float4* ap = reinterpret_cast<const float4*>(A + (size_t)n*1024 + f*16);
        float4 v0 = ap[0], v1 = ap[1], v2 = ap[2], v3 = ap[3];
        a[0]=v0.x; a[1]=v0.y; a[2]=v0.z; a[3]=v0.w;
        a[4]=v1.x; a[5]=v1.y; a[6]=v1.z; a[7]=v1.w;
        a[8]=v2.x; a[9]=v2.y; a[10]=v2.z; a[11]=v2.w;
        a[12]=v3.x; a[13]=v3.y; a[14]=v3.z; a[15]=v3.w;
    }
    int sp = spec[n];

    float wk[23];
    {
        const float* wp = w2base + (size_t)sp*(NPATHS*64) + f;
        #pragma unroll
        for (int p = 0; p < NPATHS; p++) wk[p] = wp[p*64];
    }
    float b2[16];
    #pragma unroll
    for (int k = 0; k < 16; k++) b2[k] = 0.f;
    SALLP(a, a, wk, b2)

    {
        const float* wp = w3base + (size_t)sp*(NPATHS*64) + f;
        #pragma unroll
        for (int p = 0; p < NPATHS; p++) wk[p] = wp[p*64];
    }
    float b3[16];
    #pragma unroll
    for (int k = 0; k < 16; k++) b3[k] = 0.f;
    SALLP(b2, a, wk, b3)

    float w1 = w1base[sp*64 + f];
    float4* dst4 = reinterpret_cast<float4*>(out + (size_t)n*1024 + f*16);
    float o[16];
    #pragma unroll
    for (int k = 0; k < 16; k++) o[k] = fmaf(a[k], w1, b2[k] + b3[k]);
    dst4[0] = make_float4(o[0], o[1], o[2], o[3]);
    dst4[1] = make_float4(o[4], o[5], o[6], o[7]);
    dst4[2] = make_float4(o[8], o[9], o[10], o[11]);
    dst4[3] = make_float4(o[12], o[13], o[14], o[15]);
}

// ---------------------------------------------------------------------------
// Readouts
// ---------------------------------------------------------------------------

__global__ void mace_readout0_kernel(const float* __restrict__ h,
                                     const float* __restrict__ roW,
                                     float* __restrict__ out)
{
    int n = blockIdx.x;
    int f = threadIdx.x;
    float v = h[(size_t)n*1024 + f*16] * roW[f];
    #pragma unroll
    for (int o = 32; o > 0; o >>= 1) v += __shfl_down(v, o, 64);
    if (f == 0) out[n] = v;
}

__global__ void mace_readout1_kernel(const float* __restrict__ h,
                                     const float* __restrict__ W1,
                                     const float* __restrict__ W2,
                                     float* __restrict__ out)
{
    int n = blockIdx.x;
    int f = threadIdx.x;
    __shared__ float sx[64];
    __shared__ float sz[16];
    sx[f] = h[(size_t)n*1024 + f*16];
    __syncthreads();
    if (f < 16) {
        float z = 0.f;
        #pragma unroll
        for (int g = 0; g < 64; g++) z = fmaf(sx[g], W1[g*16 + f], z);
        z = z / (1.f + expf(-z));
        sz[f] = z * W2[f];
    }
    __syncthreads();
    if (f == 0) {
        float t = 0.f;
        #pragma unroll
        for (int j = 0; j < 16; j++) t += sz[j];
        out[n] += t;
    }
}

// ---------------------------------------------------------------------------
// kernel_launch
// ---------------------------------------------------------------------------

extern "C" void kernel_launch(void* const* d_in, const int* in_sizes, int n_in,
                              void* d_out, int out_size, void* d_ws, size_t ws_size,
                              hipStream_t stream)
{
    const float* vectors = (const float*)d_in[0];
    const int*   senders = (const int*)d_in[1];
    const int*   receivers = (const int*)d_in[2];
    const int*   spec    = (const int*)d_in[3];
    const float* embed_W = (const float*)d_in[4];
    const float* skip_W  = (const float*)d_in[5];
    const float* lin1_W  = (const float*)d_in[6];
    const float* radW1   = (const float*)d_in[7];
    const float* radW2   = (const float*)d_in[8];
    const float* lin2_W  = (const float*)d_in[9];
    const float* skipf_W = (const float*)d_in[10];
    const float* prodW1  = (const float*)d_in[11];
    const float* prodW2  = (const float*)d_in[12];
    const float* prodW3  = (const float*)d_in[13];
    const float* plin_W  = (const float*)d_in[14];
    const float* ro_W    = (const float*)d_in[15];
    const float* mlp_W1  = (const float*)d_in[16];
    const float* mlp_W2  = (const float*)d_in[17];
    float* out = (float*)d_out;

    // workspace layout (floats); ~124 MB (round-16-proven layout).
    float* w   = (float*)d_ws;
    float* ysh = w;                              // E*16
    float* rbf = ysh + (size_t)NEDGE * 16;       // E*8
    float* hid = rbf + (size_t)NEDGE * 8;        // E*64 region (bf16 uses half)
    float* t0  = hid + (size_t)NEDGE * 64;       // h1 input (live in gather)
    float* t1  = t0 + NF16;                      // gather output
    float* sc  = t1 + NF16;                      // skip (layer 1)
    float* h   = sc + NF16;                      // node state / staging lo
    float* t2  = h  + NF16;                      // staging mid
    float* ext = t2 + NF16;                      // staging hi / Wc (epilogue)
    unsigned short* hidb = (unsigned short*)hid; // E*64 bf16
    unsigned short* stg = (unsigned short*)h;    // STGCAP*1472 bf16
    float* wc  = ext;                            // composed weights, 10*4*64*64
    unsigned short* wt = (unsigned short*)(ext + NF16);  // W2t bf16, 94208
    int* cnt  = (int*)((char*)wt + (size_t)RWN*64*2);    // 4096 (16B-aligned)
    int* offs = cnt + 4096;                      // 4097
    int* cur  = offs + 4097;                     // 4096
    int* eidx = cur + 4096;                      // 65536
    int* scnt  = eidx + NEDGE;                   // 16
    int* scur  = scnt + 16;                      // 16
    int* snode = scur + 16;                      // 4096

    const float EPS = 0.24253562503633297f;   // 1/sqrt(1+16)

    // CSR build (edges by receiver)
    (void)hipMemsetAsync(cnt, 0, 4096 * sizeof(int), stream);
    csr_hist_kernel<<<NEDGE/256, 256, 0, stream>>>(receivers, cnt);
    csr_scan_kernel<<<1, 1024, 0, stream>>>(cnt, offs, cur);
    csr_scatter_kernel<<<NEDGE/256, 256, 0, stream>>>(receivers, cur, eidx);

    // species sort (nodes by species)
    (void)hipMemsetAsync(scnt, 0, 32 * sizeof(int), stream);
    sp_hist_kernel<<<NNODE/256, 256, 0, stream>>>(spec, scnt);
    sp_scan_kernel<<<1, 64, 0, stream>>>(scnt, scur);
    sp_scatter_kernel<<<NNODE/256, 256, 0, stream>>>(spec, scur, snode);

    mace_geom_kernel<<<NEDGE/256, 256, 0, stream>>>(vectors, ysh, rbf);
    mace_init_h_kernel<<<(NNODE*1024)/256, 256, 0, stream>>>(spec, embed_W, h);

    dim3 ggrid((STGCAP + 63)/64, NPATHS);

    for (int layer = 0; layer < 2; layer++) {
        const float* W1 = radW1 + (size_t)layer * 8 * HDIM;
        const float* W2 = radW2 + (size_t)layer * HDIM * RWN;
        const float* l1W = lin1_W + (size_t)layer * 4 * FDIM * FDIM;
        const float* l2W = lin2_W + (size_t)layer * 4 * FDIM * FDIM;
        const float* plW = plin_W + (size_t)layer * 4 * FDIM * FDIM;
        const float* pw1 = prodW1 + (size_t)layer * NSPEC * FDIM;
        const float* pw2 = prodW2 + (size_t)layer * NSPEC * NPATHS * FDIM;
        const float* pw3 = prodW3 + (size_t)layer * NSPEC * NPATHS * FDIM;

        if (layer == 1) {
            mace_lin_sp_kernel<<<NNODE/LINB, 512, 0, stream>>>(
                h, skip_W + (size_t)1 * NSPEC * 4 * FDIM * FDIM, spec, snode,
                nullptr, sc);
        }

        mace_radial_kernel<<<(NEDGE*HDIM)/256, 256, 0, stream>>>(rbf, W1, hidb);
        w2t_kernel<<<(RWN*64 + 255)/256, 256, 0, stream>>>(W2, wt);
        mace_lin_kernel<<<NNODE/LINB, 512, 0, stream>>>(h, l1W, nullptr, t0, 1.0f);
        // h/t2/ext dead from here until after the chunk loop

        for (int c = 0; c < NCHUNK; c++) {
            int cb = c * CHUNKN;
            rw_gemm_chunk<<<ggrid, 256, 0, stream>>>(hidb, wt, offs, eidx, cb, stg);
            mace_gather_kernel<<<CHUNKN, 256, 0, stream>>>(
                t0, ysh, stg, senders, offs, eidx, cb, t1);
        }

        if (layer == 0) {
            compose_kernel<<<(NSPEC*4*64*64)/256, 256, 0, stream>>>(skipf_W, l2W, wc, EPS);
            mace_lin_sp_kernel<<<NNODE/LINB, 512, 0, stream>>>(
                t1, wc, spec, snode, nullptr, h);
            mace_prod_kernel<<<NNODE/4, 256, 0, stream>>>(h, pw1, pw2, pw3, spec, t1);
            mace_lin_kernel<<<NNODE/LINB, 512, 0, stream>>>(t1, plW, nullptr, h, 1.0f);
            mace_readout0_kernel<<<NNODE, 64, 0, stream>>>(h, ro_W, out);
        } else {
            mace_lin_kernel<<<NNODE/LINB, 512, 0, stream>>>(t1, l2W, nullptr, t2, EPS);
            mace_prod_kernel<<<NNODE/4, 256, 0, stream>>>(t2, pw1, pw2, pw3, spec, t1);
            mace_lin_kernel<<<NNODE/LINB, 512, 0, stream>>>(t1, plW, sc, t0, 1.0f);
            mace_readout1_kernel<<<NNODE, 64, 0, stream>>>(t0, mlp_W1, mlp_W2, out);
        }
    }
}